// Round 15
// baseline (84.595 us; speedup 1.0000x reference)
//
#include <hip/hip_runtime.h>
#include <hip/hip_bf16.h>
#include <math.h>

#define NN 48

typedef __attribute__((ext_vector_type(8))) short bf16x8;
typedef __attribute__((ext_vector_type(4))) float f32x4;

__device__ __forceinline__ float sigmoidf_(float x) {
    return 1.0f / (1.0f + __expf(-x));
}

__device__ __forceinline__ unsigned short f2bf(float f) {
    __hip_bfloat16 h = __float2bfloat16(f);
    unsigned short u;
    __builtin_memcpy(&u, &h, 2);
    return u;
}

__device__ __forceinline__ unsigned packbf2(float a, float b) {
    return (unsigned)f2bf(a) | ((unsigned)f2bf(b) << 16);
}

// ================= kernel A (k_pre): fused reduce3 + x3bf (natural only) + x2bf/x2t + weights
// blocks [0,2304):   reduce3 (4 pos/block, shfl tree over k) + emit x3bf (coalesced)
// blocks [2304,2340): x2 -> x2bf + x2t (x2t[b][q][p] = x2[b][p][q])
// block 2340:        W1_3/W2_3 -> bf16 MFMA B-fragments.
// r3[pos][2c]=max_{k not in {i,j}} (0-folded), [2c+1]=min (1-folded); i==j -> 0/1.
__global__ __launch_bounds__(256) void k_pre(const float* __restrict__ x2, const float* __restrict__ x3,
        const float* __restrict__ W1, const float* __restrict__ W2,
        float* __restrict__ r3, unsigned short* __restrict__ wf,
        unsigned short* __restrict__ x2bf, unsigned short* __restrict__ x2t,
        unsigned short* __restrict__ x3bf, int emit) {
    int tid = threadIdx.x, blk = blockIdx.x;
    if (blk < 2304) {
        int posl = tid >> 6, l = tid & 63;
        int pos = blk * 4 + posl;              // (b*48+i)*48+j < 9216
        int j = pos % NN;
        int bi = pos / NN;                     // b*48+i
        int i = bi % NN;
        int cq = l & 3, kkb = l >> 2;          // cq: channel quad, kkb: 0..15
        float4 ex = make_float4(0.f, 0.f, 0.f, 0.f);
        float4 fa = make_float4(1.f, 1.f, 1.f, 1.f);
        #pragma unroll
        for (int s = 0; s < 3; ++s) {
            int kk = kkb + s * 16;             // 0..47
            size_t idx = (((size_t)pos * NN + kk) << 4) + (cq << 2);
            float4 v = *(const float4*)(x3 + idx);
            if (emit) {
                uint2 pk;
                pk.x = packbf2(v.x, v.y);
                pk.y = packbf2(v.z, v.w);
                *(uint2*)(x3bf + idx) = pk;
            }
            bool ok = (i != j) && (kk != i) && (kk != j);
            ex.x = fmaxf(ex.x, ok ? v.x : 0.f);  fa.x = fminf(fa.x, ok ? v.x : 1.f);
            ex.y = fmaxf(ex.y, ok ? v.y : 0.f);  fa.y = fminf(fa.y, ok ? v.y : 1.f);
            ex.z = fmaxf(ex.z, ok ? v.z : 0.f);  fa.z = fminf(fa.z, ok ? v.z : 1.f);
            ex.w = fmaxf(ex.w, ok ? v.w : 0.f);  fa.w = fminf(fa.w, ok ? v.w : 1.f);
        }
        #pragma unroll
        for (int m = 4; m <= 32; m <<= 1) {
            ex.x = fmaxf(ex.x, __shfl_xor(ex.x, m));  fa.x = fminf(fa.x, __shfl_xor(fa.x, m));
            ex.y = fmaxf(ex.y, __shfl_xor(ex.y, m));  fa.y = fminf(fa.y, __shfl_xor(fa.y, m));
            ex.z = fmaxf(ex.z, __shfl_xor(ex.z, m));  fa.z = fminf(fa.z, __shfl_xor(fa.z, m));
            ex.w = fmaxf(ex.w, __shfl_xor(ex.w, m));  fa.w = fminf(fa.w, __shfl_xor(fa.w, m));
        }
        if (kkb == 0) {
            float* dst = r3 + ((size_t)pos << 5) + (cq << 3);
            *(float4*)dst       = make_float4(ex.x, fa.x, ex.y, fa.y);
            *(float4*)(dst + 4) = make_float4(ex.z, fa.z, ex.w, fa.w);
        }
    } else if (blk < 2340) {
        if (!emit) return;
        int bb = blk - 2304;                   // 0..35
        #pragma unroll
        for (int q4 = 0; q4 < 4; ++q4) {
            int e = bb * 1024 + q4 * 256 + tid; // float4 chunk < 36864
            int off = e << 2;                   // float offset < 147456
            float4 v = *(const float4*)(x2 + off);
            uint2 pk;
            pk.x = packbf2(v.x, v.y);
            pk.y = packbf2(v.z, v.w);
            *(uint2*)(x2bf + off) = pk;
            int c = off & 15;
            int r = off >> 4;                   // (b*48+p)*48+q
            int q = r % NN;
            int bp = r / NN;
            int p = bp % NN;
            int b_ = bp / NN;
            int ti = (((b_ * NN + q) * NN + p) << 4) + c;
            *(uint2*)(x2t + ti) = pk;
        }
    } else {
        for (int e = tid; e < 13312; e += 256) {
            unsigned short v;
            if (e < 12288) {
                int idx = e & 7, l = (e >> 3) & 63, r = e >> 9;   // r = nt*6+ks
                int ks = r % 6, nt = r / 6;
                v = f2bf(W1[(ks * 32 + ((l >> 4) << 3) + idx) * 64 + (nt << 4) + (l & 15)]);
            } else {
                int e2 = e - 12288;
                int idx = e2 & 7, l = (e2 >> 3) & 63, ks = e2 >> 9;
                v = f2bf(W2[(ks * 32 + ((l >> 4) << 3) + idx) * 16 + (l & 15)]);
            }
            wf[e] = v;
        }
    }
}

// ================= kernel A2 (k_tr): build Z and Y from x3bf via LDS tile transpose ==========
// Z[b][p][q][k] = x3[b][p][k][q]  (writer form: Z[b,i,kk,j] <- x3[b,i,j,kk])
// Y[b][p][q][k] = x3[b][k][p][q]  (writer form: Y[b,j,kk,i] <- x3[b,i,j,kk])
// blocks 0..191: Z plane (b,i). blocks 192..383: Y plane (b,j). 2 half-planes of 24 rows.
// LDS rows padded to 776 elems (1552 B: 16B-aligned, low bank conflict). Reads & writes
// coalesced (src rows 1536 B contiguous; dst 768 B chunks per kk).
__global__ __launch_bounds__(256) void k_tr(const unsigned short* __restrict__ x3bf,
        unsigned short* __restrict__ zbf, unsigned short* __restrict__ ybf) {
    __shared__ __align__(16) unsigned short lds[24 * 776];   // 37.2 KB
    int tid = threadIdx.x;
    int blk = blockIdx.x;                 // 0..383
    int isY = (blk >= 192) ? 1 : 0;
    int plane = isY ? blk - 192 : blk;    // b*48 + a  (a = i for Z, j for Y)
    int b = plane / NN, a = plane % NN;
    const unsigned short* src;
    unsigned short* dst;
    size_t srow;
    if (!isY) {
        src = x3bf + (size_t)plane * 36864;                      // rows j, contiguous 768
        dst = zbf + (size_t)plane * 36864;
        srow = 768;
    } else {
        src = x3bf + (size_t)b * NN * 36864 + (size_t)a * 768;   // rows i at stride 36864
        dst = ybf + (size_t)plane * 36864;
        srow = 36864;
    }
    for (int h = 0; h < 2; ++h) {
        int r0 = h * 24;
        // load 24 rows x 768 elems (uint4 = 8 elems): 2304 loads = 9 x 256
        #pragma unroll
        for (int it = 0; it < 9; ++it) {
            int g = it * 256 + tid;
            int r = g / 96;                      // 96 uint4 per row
            int e = (g - r * 96) << 3;
            *(uint4*)&lds[r * 776 + e] = *(const uint4*)&src[(size_t)(r0 + r) * srow + e];
        }
        __syncthreads();
        // write: dst elem o = kk*768 + (r0+r)*16 + c  <- lds[r*776 + kk*16 + c]
        #pragma unroll
        for (int it = 0; it < 9; ++it) {
            int g = it * 256 + tid;
            int kk = g / 48;                     // 48 uint4 per kk (24 rows x 16 / 8)
            int rem = (g - kk * 48) << 3;
            int r = rem >> 4;
            int c = rem & 15;                    // 0 or 8
            uint4 v = *(const uint4*)&lds[r * 776 + kk * 16 + c];
            *(uint4*)&dst[(size_t)kk * 768 + (r0 + r) * 16 + c] = v;
        }
        __syncthreads();
    }
}

// ================= kernel B: g0 (block 0) + g1 w/ fused reduce2 (1..48) + g2 (49..624) ==========
__global__ __launch_bounds__(256) void k_small(const float* __restrict__ x0, const float* __restrict__ x1,
        const float* __restrict__ x2, const float* __restrict__ r3,
        const float* __restrict__ W1_0, const float* __restrict__ b1_0,
        const float* __restrict__ W2_0, const float* __restrict__ b2_0,
        const float* __restrict__ W1_1, const float* __restrict__ b1_1,
        const float* __restrict__ W2_1, const float* __restrict__ b2_1,
        const float* __restrict__ W1_2, const float* __restrict__ b1_2,
        const float* __restrict__ W2_2, const float* __restrict__ b2_2,
        float* __restrict__ out) {
    __shared__ __align__(16) float smem[8960];
    int tid = threadIdx.x;
    int blk = blockIdx.x;
    if (blk == 0) {
        float* st0 = smem;            // [4][48]
        float* sh0 = smem + 192;      // [4][64]
        int b = tid >> 6, sub = (tid >> 4) & 3, c = tid & 15;
        float ex = -INFINITY, fa = INFINITY;
        for (int ii = sub * 12; ii < sub * 12 + 12; ++ii) {
            float v = x1[(b * NN + ii) * 16 + c];
            ex = fmaxf(ex, v); fa = fminf(fa, v);
        }
        ex = fmaxf(ex, __shfl_xor(ex, 16)); fa = fminf(fa, __shfl_xor(fa, 16));
        ex = fmaxf(ex, __shfl_xor(ex, 32)); fa = fminf(fa, __shfl_xor(fa, 32));
        if (sub == 0) { st0[b * 48 + 16 + 2 * c] = ex; st0[b * 48 + 17 + 2 * c] = fa; }
        if (tid < 64) st0[(tid >> 4) * 48 + (tid & 15)] = x0[tid];
        __syncthreads();
        {
            int bb = tid >> 6, ln = tid & 63;
            float h = b1_0[ln];
            for (int cc = 0; cc < 48; ++cc) h += st0[bb * 48 + cc] * W1_0[cc * 64 + ln];
            sh0[bb * 64 + ln] = fmaxf(h, 0.f);
        }
        __syncthreads();
        if (tid < 64) {
            int bb = tid >> 4, o = tid & 15;
            float acc = b2_0[o];
            for (int tt = 0; tt < 64; ++tt) acc += sh0[bb * 64 + tt] * W2_0[tt * 16 + o];
            out[bb * 16 + o] = sigmoidf_(acc);
        }
    } else if (blk <= 48) {
        int grp = tid >> 6, ln = tid & 63;
        int row = (blk - 1) * 4 + grp;             // b*48+i, < 192
        int b = row / NN, i = row % NN;
        float* sin1 = smem + grp * 64;
        float* sh1  = smem + 256 + grp * 64;
        int c = ln & 15, q = ln >> 4;
        float ex = 0.f, fa = 1.f;
        const float* xb = x2 + (size_t)row * NN * 16 + c;
        for (int jj = q * 12; jj < q * 12 + 12; ++jj) {
            float v = xb[jj * 16];
            bool ok = (jj != i);
            ex = fmaxf(ex, ok ? v : 0.f); fa = fminf(fa, ok ? v : 1.f);
        }
        ex = fmaxf(ex, __shfl_xor(ex, 16)); fa = fminf(fa, __shfl_xor(fa, 16));
        ex = fmaxf(ex, __shfl_xor(ex, 32)); fa = fminf(fa, __shfl_xor(fa, 32));
        if (q == 0) { sin1[32 + 2 * c] = ex; sin1[33 + 2 * c] = fa; }
        if (ln < 16) sin1[ln] = x0[b * 16 + ln];
        else if (ln < 32) sin1[ln] = x1[row * 16 + (ln - 16)];
        __syncthreads();
        float h = b1_1[ln];
        #pragma unroll
        for (int c4 = 0; c4 < 64; c4 += 4) {
            float4 iv = *(const float4*)&sin1[c4];
            h += iv.x * W1_1[(c4 + 0) * 64 + ln] + iv.y * W1_1[(c4 + 1) * 64 + ln]
               + iv.z * W1_1[(c4 + 2) * 64 + ln] + iv.w * W1_1[(c4 + 3) * 64 + ln];
        }
        sh1[ln] = fmaxf(h, 0.f);
        __syncthreads();
        if (ln < 16) {
            float acc = b2_1[ln];
            #pragma unroll
            for (int tt = 0; tt < 64; ++tt) acc += sh1[tt] * W2_1[tt * 16 + ln];
            out[64 + row * 16 + ln] = sigmoidf_(acc);
        }
    } else {
        float* sW1  = smem;            // 8192
        float* sin_ = smem + 8192;     // [4][128]
        float* sh   = smem + 8704;     // [4][64]
        int wv = tid >> 6, ln = tid & 63;
        for (int p = tid; p < 8192; p += 256) sW1[p] = W1_2[p];
        float bias = b1_2[ln];
        __syncthreads();
        for (int rr = 0; rr < 4; ++rr) {
            int row = (blk - 49) * 16 + rr * 4 + wv;   // (b*48+i)*48+j
            int j = row % NN;
            int bi = row / NN;
            int i = bi % NN;
            int b = bi / NN;
            for (int cc = ln; cc < 128; cc += 64) {
                int half = cc >> 6, w = cc & 63;
                int a1 = half ? j : i;
                int a2 = half ? i : j;
                float v;
                if (w < 16)      v = x1[(b * NN + a1) * 16 + w];
                else if (w < 32) v = x2[((b * NN + a1) * NN + a2) * 16 + (w - 16)];
                else             v = r3[((size_t)(b * NN + a1) * NN + a2) * 32 + (w - 32)];
                sin_[wv * 128 + cc] = v;
            }
            __syncthreads();
            float h = bias;
            #pragma unroll
            for (int c4 = 0; c4 < 128; c4 += 4) {
                float4 iv = *(const float4*)&sin_[wv * 128 + c4];
                h += iv.x * sW1[(c4 + 0) * 64 + ln] + iv.y * sW1[(c4 + 1) * 64 + ln]
                   + iv.z * sW1[(c4 + 2) * 64 + ln] + iv.w * sW1[(c4 + 3) * 64 + ln];
            }
            sh[wv * 64 + ln] = fmaxf(h, 0.f);
            __syncthreads();
            if (ln < 16) {
                float acc = b2_2[ln];
                #pragma unroll
                for (int tt = 0; tt < 64; ++tt) acc += sh[wv * 64 + tt] * W2_2[tt * 16 + ln];
                out[3136 + row * 16 + ln] = sigmoidf_(acc);
            }
            __syncthreads();
        }
    }
}

// ================= kernel C (fast): group 3, mt-per-wave paired MFMA, COALESCED gather ======
// Block = (pair i<=j, batch b), 192 threads = 3 waves, wave = M-tile mt. All fragments
// kk-innermost via layouts {x3bf, Z, Y} + x2t. Offsets relative to bf16 ws base (x2bf):
// x2t +147456, x3 +294912, Z +7372800, Y +14450688. (r14-verified)
__global__ __launch_bounds__(192) void k_g3d(const unsigned short* __restrict__ wsb,
        const unsigned short* __restrict__ wf,
        const float* __restrict__ b1, const float* __restrict__ b2,
        float* __restrict__ out3) {
    __shared__ __align__(16) unsigned short sH[2][6 * 64 * 8];   // 12 KB

    int tid = threadIdx.x, mt = tid >> 6, l = tid & 63;   // wave = M-tile 0..2
    int pp = blockIdx.x, i = 0;
    while (pp >= NN - i) { pp -= NN - i; ++i; }
    int j = i + pp;                               // i <= j
    int b = blockIdx.y;

    bf16x8 w1f[4][6];
    #pragma unroll
    for (int nt = 0; nt < 4; ++nt)
        #pragma unroll
        for (int ks = 0; ks < 6; ++ks)
            w1f[nt][ks] = *(const bf16x8*)(wf + (((nt * 6 + ks) << 6) + l) * 8);
    bf16x8 w2f[2];
    #pragma unroll
    for (int ks = 0; ks < 2; ++ks)
        w2f[ks] = *(const bf16x8*)(wf + 12288 + ((ks << 6) + l) * 8);

    const int b2b = b * 36864;
    const int b3b = b * 1769472;
    const int p1[6] = { 2, 4, 0, 5, 1, 3 };

    int l15 = l & 15, g = l >> 4;
    bool isx2 = (g < 2);
    int goff = (g & 1) << 3;
    int ij16 = (i * NN + j) * 16, ji16 = (j * NN + i) * 16;
    int row16 = ((mt << 4) + l15) << 4;

    int off_[6];
    if (isx2) {
        off_[0] = b2b + ij16 + goff;
        off_[1] = b2b + i * 768 + row16 + goff;
        off_[2] = b2b + ji16 + goff;
        off_[3] = 147456 + b2b + i * 768 + row16 + goff;
        off_[4] = b2b + j * 768 + row16 + goff;
        off_[5] = 147456 + b2b + j * 768 + row16 + goff;
    } else {
        int ij768 = (i * NN + j) * 768, ji768 = (j * NN + i) * 768;
        off_[0] = 294912   + b3b + ij768 + row16 + goff;
        off_[1] = 7372800  + b3b + ij768 + row16 + goff;
        off_[2] = 294912   + b3b + ji768 + row16 + goff;
        off_[3] = 14450688 + b3b + ij768 + row16 + goff;
        off_[4] = 7372800  + b3b + ji768 + row16 + goff;
        off_[5] = 14450688 + b3b + ji768 + row16 + goff;
    }

    f32x4 acc[4][2];
    #pragma unroll
    for (int nt = 0; nt < 4; ++nt) {
        float bv = b1[(nt << 4) + l15];
        f32x4 t = {bv, bv, bv, bv};
        acc[nt][0] = t; acc[nt][1] = t;
    }

    #pragma unroll
    for (int f = 0; f < 6; ++f) {
        bf16x8 a = *(const bf16x8*)(wsb + off_[f]);
        #pragma unroll
        for (int nt = 0; nt < 4; ++nt) {
            acc[nt][0] = __builtin_amdgcn_mfma_f32_16x16x32_bf16(a, w1f[nt][f], acc[nt][0], 0, 0, 0);
            acc[nt][1] = __builtin_amdgcn_mfma_f32_16x16x32_bf16(a, w1f[nt][p1[f]], acc[nt][1], 0, 0, 0);
        }
    }

    {
        int rbase = (l >> 4) << 2;
        #pragma unroll
        for (int tr = 0; tr < 2; ++tr) {
            #pragma unroll
            for (int nt = 0; nt < 4; ++nt) {
                int within = ((nt & 1) << 4) + l15;
                int ks2 = nt >> 1;
                int lhi = (within >> 3) << 4;
                int idx = within & 7;
                #pragma unroll
                for (int rg = 0; rg < 4; ++rg) {
                    float h = fmaxf(acc[nt][tr][rg], 0.0f);
                    int lp = rbase + rg + lhi;
                    sH[tr][((((mt << 1) + ks2) << 6) + lp) * 8 + idx] = f2bf(h);
                }
            }
        }
    }
    // no barrier: wave mt writes/reads only segments 2mt, 2mt+1

    {
        float bv2 = b2[l15];
        #pragma unroll
        for (int tr = 0; tr < 2; ++tr) {
            if (tr == 0 || i != j) {
                f32x4 acc2 = {bv2, bv2, bv2, bv2};
                #pragma unroll
                for (int ks = 0; ks < 2; ++ks) {
                    bf16x8 a = *(const bf16x8*)&sH[tr][((((mt << 1) + ks) << 6) + l) << 3];
                    acc2 = __builtin_amdgcn_mfma_f32_16x16x32_bf16(a, w2f[ks], acc2, 0, 0, 0);
                }
                int triple = tr ? ((b * NN + j) * NN + i) : ((b * NN + i) * NN + j);
                size_t obase = ((size_t)triple * NN + (mt << 4) + ((l >> 4) << 2)) * 16 + l15;
                #pragma unroll
                for (int rg = 0; rg < 4; ++rg)
                    out3[obase + (size_t)rg * 16] = sigmoidf_(acc2[rg]);
            }
        }
    }
}

// ================= kernel C (fallback): round-4-verified fp32 staged version =================
__global__ __launch_bounds__(256) void k_g3m(const float* __restrict__ x2, const float* __restrict__ x3,
                                             const unsigned short* __restrict__ wf,
                                             const float* __restrict__ b1, const float* __restrict__ b2,
                                             float* __restrict__ out3) {
    __shared__ __align__(16) unsigned short sA[18 * 64 * 8];
    __shared__ __align__(16) unsigned short sH[6 * 64 * 8];

    int tid = threadIdx.x;
    int wv = tid >> 6, l = tid & 63;
    int triple = blockIdx.x;
    int j = triple % NN;
    int bi = triple / NN;
    int i = bi % NN;
    int b = bi / NN;

    bf16x8 w1f[6];
    #pragma unroll
    for (int ks = 0; ks < 6; ++ks)
        w1f[ks] = *(const bf16x8*)(wf + (((wv * 6 + ks) << 6) + l) * 8);
    bf16x8 w2f[2];
    #pragma unroll
    for (int ks = 0; ks < 2; ++ks)
        w2f[ks] = *(const bf16x8*)(wf + 12288 + ((ks << 6) + l) * 8);

    const int x2b = b * NN * NN * 16;
    const int x3b = b * NN * NN * NN * 16;

    #pragma unroll
    for (int it = 0; it < 9; ++it) {
        int t = it * 256 + tid;
        int fs = __builtin_amdgcn_readfirstlane(t >> 7);
        int mt = fs / 6;
        int ks = fs - mt * 6;
        int lp = (t >> 1) & 63;
        int kk = (mt << 4) + (lp & 15);
        int w = ((lp >> 4) << 3) + ((t & 1) << 2);
        int a1, a2, a3;
        switch (ks) {
            case 0:  a1 = i;  a2 = j;  a3 = kk; break;
            case 1:  a1 = i;  a2 = kk; a3 = j;  break;
            case 2:  a1 = j;  a2 = i;  a3 = kk; break;
            case 3:  a1 = kk; a2 = i;  a3 = j;  break;
            case 4:  a1 = j;  a2 = kk; a3 = i;  break;
            default: a1 = kk; a2 = j;  a3 = i;  break;
        }
        const float* p2 = x2 + x2b + (a1 * NN + a2) * 16 + w;
        const float* p3 = x3 + x3b + ((a1 * NN + a2) * NN + a3) * 16 + (w - 16);
        const float* p = (w < 16) ? p2 : p3;
        float4 v = *(const float4*)p;
        uint2 pk;
        pk.x = packbf2(v.x, v.y);
        pk.y = packbf2(v.z, v.w);
        *(uint2*)&sA[t * 4] = pk;
    }
    __syncthreads();

    float bv = b1[(wv << 4) + (l & 15)];
    f32x4 acc0 = {bv, bv, bv, bv};
    f32x4 acc1 = acc0, acc2 = acc0;
    #pragma unroll
    for (int ks = 0; ks < 6; ++ks) {
        bf16x8 a0  = *(const bf16x8*)&sA[(((0 * 6 + ks) << 6) + l) << 3];
        bf16x8 a1_ = *(const bf16x8*)&sA[(((1 * 6 + ks) << 6) + l) << 3];
        bf16x8 a2_ = *(const bf16x8*)&sA[(((2 * 6 + ks) << 6) + l) << 3];
        acc0 = __builtin_amdgcn_mfma_f32_16x16x32_bf16(a0,  w1f[ks], acc0, 0, 0, 0);
        acc1 = __builtin_amdgcn_mfma_f32_16x16x32_bf16(a1_, w1f[ks], acc1, 0, 0, 0);
        acc2 = __builtin_amdgcn_mfma_f32_16x16x32_bf16(a2_, w1f[ks], acc2, 0, 0, 0);
    }

    {
        int within = ((wv & 1) << 4) + (l & 15);
        int ks2 = wv >> 1;
        int lhi = (within >> 3) << 4;
        int idx = within & 7;
        int rbase = (l >> 4) << 2;
        #pragma unroll
        for (int mt = 0; mt < 3; ++mt) {
            f32x4 a = (mt == 0) ? acc0 : (mt == 1) ? acc1 : acc2;
            #pragma unroll
            for (int rg = 0; rg < 4; ++rg) {
                float h = fmaxf(a[rg], 0.0f);
                int lp = rbase + rg + lhi;
                sH[((((mt << 1) + ks2) << 6) + lp) * 8 + idx] = f2bf(h);
            }
        }
    }
    __syncthreads();

    if (wv < 3) {
        int mt = wv;
        float bv2 = b2[l & 15];
        f32x4 acc = {bv2, bv2, bv2, bv2};
        #pragma unroll
        for (int ks = 0; ks < 2; ++ks) {
            bf16x8 a = *(const bf16x8*)&sH[((((mt << 1) + ks) << 6) + l) << 3];
            acc = __builtin_amdgcn_mfma_f32_16x16x32_bf16(a, w2f[ks], acc, 0, 0, 0);
        }
        size_t obase = ((size_t)triple * NN + (mt << 4) + ((l >> 4) << 2)) * 16 + (l & 15);
        #pragma unroll
        for (int rg = 0; rg < 4; ++rg)
            out3[obase + (size_t)rg * 16] = sigmoidf_(acc[rg]);
    }
}

extern "C" void kernel_launch(void* const* d_in, const int* in_sizes, int n_in,
                              void* d_out, int out_size, void* d_ws, size_t ws_size,
                              hipStream_t stream) {
    const float* x0 = (const float*)d_in[0];
    const float* x1 = (const float*)d_in[1];
    const float* x2 = (const float*)d_in[2];
    const float* x3 = (const float*)d_in[3];
    const float* W1_0 = (const float*)d_in[4];
    const float* b1_0 = (const float*)d_in[5];
    const float* W2_0 = (const float*)d_in[6];
    const float* b2_0 = (const float*)d_in[7];
    const float* W1_1 = (const float*)d_in[8];
    const float* b1_1 = (const float*)d_in[9];
    const float* W2_1 = (const float*)d_in[10];
    const float* b2_1 = (const float*)d_in[11];
    const float* W1_2 = (const float*)d_in[12];
    const float* b1_2 = (const float*)d_in[13];
    const float* W2_2 = (const float*)d_in[14];
    const float* b2_2 = (const float*)d_in[15];
    const float* W1_3 = (const float*)d_in[16];
    const float* b1_3 = (const float*)d_in[17];
    const float* W2_3 = (const float*)d_in[18];
    const float* b2_3 = (const float*)d_in[19];

    float* out = (float*)d_out;
    float* r3 = (float*)d_ws;                               // 294912 f32
    unsigned short* wf   = (unsigned short*)(r3 + 294912);  // 13312 bf16
    unsigned short* x2bf = wf + 13312;                      // 147456   (bf16 ws base for k_g3d)
    unsigned short* x2t  = x2bf + 147456;                   // 147456
    unsigned short* x3bf = x2t + 147456;                    // 7077888
    unsigned short* zbf  = x3bf + 7077888;                  // 7077888
    unsigned short* ybf  = zbf + 7077888;                   // 7077888
    size_t need = (size_t)294912 * 4
                + (size_t)(13312 + 2 * 147456 + 3 * 7077888) * 2;   // ~44.3 MB
    int fast = (ws_size >= need) ? 1 : 0;

    hipLaunchKernelGGL(k_pre, dim3(2341), dim3(256), 0, stream,
                       x2, x3, W1_3, W2_3, r3, wf, x2bf, x2t, x3bf, fast);
    if (fast) {
        hipLaunchKernelGGL(k_tr, dim3(384), dim3(256), 0, stream, x3bf, zbf, ybf);
        hipLaunchKernelGGL(k_g3d, dim3(1176, 4), dim3(192), 0, stream,
                           x2bf, wf, b1_3, b2_3, out + 150592);
    } else {
        hipLaunchKernelGGL(k_g3m, dim3(9216), dim3(256), 0, stream,
                           x2, x3, wf, b1_3, b2_3, out + 150592);
    }
    hipLaunchKernelGGL(k_small, dim3(625), dim3(256), 0, stream,
                       x0, x1, x2, r3,
                       W1_0, b1_0, W2_0, b2_0,
                       W1_1, b1_1, W2_1, b2_1,
                       W1_2, b1_2, W2_2, b2_2,
                       out);
}

// Round 16
// 78.389 us; speedup vs baseline: 1.0792x; 1.0792x over previous
//
#include <hip/hip_runtime.h>
#include <hip/hip_bf16.h>
#include <math.h>

#define NN 48

typedef __attribute__((ext_vector_type(8))) short bf16x8;
typedef __attribute__((ext_vector_type(4))) float f32x4;

__device__ __forceinline__ float sigmoidf_(float x) {
    return 1.0f / (1.0f + __expf(-x));
}

__device__ __forceinline__ unsigned short f2bf(float f) {
    __hip_bfloat16 h = __float2bfloat16(f);
    unsigned short u;
    __builtin_memcpy(&u, &h, 2);
    return u;
}

__device__ __forceinline__ unsigned packbf2(float a, float b) {
    return (unsigned)f2bf(a) | ((unsigned)f2bf(b) << 16);
}

// ================= kernel A (k_pre): fused reduce3 + multi-layout bf16 emission + weights ====
// blocks [0,2304):   reduce3 (4 pos/block, shfl tree over k) + emit x3bf / Z / Y (x3 read ONCE)
//                    Z[b][p][q][k] = x3[b][p][k][q]   (element x3[b][i][j][kk] -> Z[b][i][kk][j])
//                    Y[b][p][q][k] = x3[b][k][p][q]   (element x3[b][i][j][kk] -> Y[b][j][kk][i])
// blocks [2304,2340): x2 -> x2bf + x2t (x2t[b][q][p] = x2[b][p][q])
// block 2340:        W1_3/W2_3 -> bf16 MFMA B-fragments.
// r3[pos][2c]=max_{k not in {i,j}} (0-folded), [2c+1]=min (1-folded); i==j -> 0/1.
__global__ __launch_bounds__(256) void k_pre(const float* __restrict__ x2, const float* __restrict__ x3,
        const float* __restrict__ W1, const float* __restrict__ W2,
        float* __restrict__ r3, unsigned short* __restrict__ wf,
        unsigned short* __restrict__ x2bf, unsigned short* __restrict__ x2t,
        unsigned short* __restrict__ x3bf, unsigned short* __restrict__ zbf,
        unsigned short* __restrict__ ybf, int emit) {
    int tid = threadIdx.x, blk = blockIdx.x;
    if (blk < 2304) {
        int posl = tid >> 6, l = tid & 63;
        int pos = blk * 4 + posl;              // (b*48+i)*48+j < 9216
        int j = pos % NN;
        int bi = pos / NN;                     // b*48+i
        int i = bi % NN;
        int b = bi / NN;
        int cq = l & 3, kkb = l >> 2;          // cq: channel quad, kkb: 0..15
        float4 ex = make_float4(0.f, 0.f, 0.f, 0.f);
        float4 fa = make_float4(1.f, 1.f, 1.f, 1.f);
        #pragma unroll
        for (int s = 0; s < 3; ++s) {
            int kk = kkb + s * 16;             // 0..47
            size_t idx = (((size_t)pos * NN + kk) << 4) + (cq << 2);
            float4 v = *(const float4*)(x3 + idx);
            if (emit) {
                uint2 pk;
                pk.x = packbf2(v.x, v.y);
                pk.y = packbf2(v.z, v.w);
                *(uint2*)(x3bf + idx) = pk;
                size_t zi = ((size_t)bi * NN + kk) * 768 + j * 16 + (cq << 2);
                *(uint2*)(zbf + zi) = pk;
                size_t yi = ((size_t)(b * NN + j) * NN + kk) * 768 + i * 16 + (cq << 2);
                *(uint2*)(ybf + yi) = pk;
            }
            bool ok = (i != j) && (kk != i) && (kk != j);
            ex.x = fmaxf(ex.x, ok ? v.x : 0.f);  fa.x = fminf(fa.x, ok ? v.x : 1.f);
            ex.y = fmaxf(ex.y, ok ? v.y : 0.f);  fa.y = fminf(fa.y, ok ? v.y : 1.f);
            ex.z = fmaxf(ex.z, ok ? v.z : 0.f);  fa.z = fminf(fa.z, ok ? v.z : 1.f);
            ex.w = fmaxf(ex.w, ok ? v.w : 0.f);  fa.w = fminf(fa.w, ok ? v.w : 1.f);
        }
        #pragma unroll
        for (int m = 4; m <= 32; m <<= 1) {
            ex.x = fmaxf(ex.x, __shfl_xor(ex.x, m));  fa.x = fminf(fa.x, __shfl_xor(fa.x, m));
            ex.y = fmaxf(ex.y, __shfl_xor(ex.y, m));  fa.y = fminf(fa.y, __shfl_xor(fa.y, m));
            ex.z = fmaxf(ex.z, __shfl_xor(ex.z, m));  fa.z = fminf(fa.z, __shfl_xor(fa.z, m));
            ex.w = fmaxf(ex.w, __shfl_xor(ex.w, m));  fa.w = fminf(fa.w, __shfl_xor(fa.w, m));
        }
        if (kkb == 0) {
            float* dst = r3 + ((size_t)pos << 5) + (cq << 3);
            *(float4*)dst       = make_float4(ex.x, fa.x, ex.y, fa.y);
            *(float4*)(dst + 4) = make_float4(ex.z, fa.z, ex.w, fa.w);
        }
    } else if (blk < 2340) {
        if (!emit) return;
        int bb = blk - 2304;                   // 0..35
        #pragma unroll
        for (int q4 = 0; q4 < 4; ++q4) {
            int e = bb * 1024 + q4 * 256 + tid; // float4 chunk < 36864
            int off = e << 2;                   // float offset < 147456
            float4 v = *(const float4*)(x2 + off);
            uint2 pk;
            pk.x = packbf2(v.x, v.y);
            pk.y = packbf2(v.z, v.w);
            *(uint2*)(x2bf + off) = pk;
            int c = off & 15;
            int r = off >> 4;                   // (b*48+p)*48+q
            int q = r % NN;
            int bp = r / NN;
            int p = bp % NN;
            int b_ = bp / NN;
            int ti = (((b_ * NN + q) * NN + p) << 4) + c;
            *(uint2*)(x2t + ti) = pk;
        }
    } else {
        for (int e = tid; e < 13312; e += 256) {
            unsigned short v;
            if (e < 12288) {
                int idx = e & 7, l = (e >> 3) & 63, r = e >> 9;   // r = nt*6+ks
                int ks = r % 6, nt = r / 6;
                v = f2bf(W1[(ks * 32 + ((l >> 4) << 3) + idx) * 64 + (nt << 4) + (l & 15)]);
            } else {
                int e2 = e - 12288;
                int idx = e2 & 7, l = (e2 >> 3) & 63, ks = e2 >> 9;
                v = f2bf(W2[(ks * 32 + ((l >> 4) << 3) + idx) * 16 + (l & 15)]);
            }
            wf[e] = v;
        }
    }
}

// ================= kernel B: g0 (block 0) + g1 w/ fused reduce2 (1..48) + g2 (49..624) ==========
__global__ __launch_bounds__(256) void k_small(const float* __restrict__ x0, const float* __restrict__ x1,
        const float* __restrict__ x2, const float* __restrict__ r3,
        const float* __restrict__ W1_0, const float* __restrict__ b1_0,
        const float* __restrict__ W2_0, const float* __restrict__ b2_0,
        const float* __restrict__ W1_1, const float* __restrict__ b1_1,
        const float* __restrict__ W2_1, const float* __restrict__ b2_1,
        const float* __restrict__ W1_2, const float* __restrict__ b1_2,
        const float* __restrict__ W2_2, const float* __restrict__ b2_2,
        float* __restrict__ out) {
    __shared__ __align__(16) float smem[8960];
    int tid = threadIdx.x;
    int blk = blockIdx.x;
    if (blk == 0) {
        float* st0 = smem;            // [4][48]
        float* sh0 = smem + 192;      // [4][64]
        int b = tid >> 6, sub = (tid >> 4) & 3, c = tid & 15;
        float ex = -INFINITY, fa = INFINITY;
        for (int ii = sub * 12; ii < sub * 12 + 12; ++ii) {
            float v = x1[(b * NN + ii) * 16 + c];
            ex = fmaxf(ex, v); fa = fminf(fa, v);
        }
        ex = fmaxf(ex, __shfl_xor(ex, 16)); fa = fminf(fa, __shfl_xor(fa, 16));
        ex = fmaxf(ex, __shfl_xor(ex, 32)); fa = fminf(fa, __shfl_xor(fa, 32));
        if (sub == 0) { st0[b * 48 + 16 + 2 * c] = ex; st0[b * 48 + 17 + 2 * c] = fa; }
        if (tid < 64) st0[(tid >> 4) * 48 + (tid & 15)] = x0[tid];
        __syncthreads();
        {
            int bb = tid >> 6, ln = tid & 63;
            float h = b1_0[ln];
            for (int cc = 0; cc < 48; ++cc) h += st0[bb * 48 + cc] * W1_0[cc * 64 + ln];
            sh0[bb * 64 + ln] = fmaxf(h, 0.f);
        }
        __syncthreads();
        if (tid < 64) {
            int bb = tid >> 4, o = tid & 15;
            float acc = b2_0[o];
            for (int tt = 0; tt < 64; ++tt) acc += sh0[bb * 64 + tt] * W2_0[tt * 16 + o];
            out[bb * 16 + o] = sigmoidf_(acc);
        }
    } else if (blk <= 48) {
        int grp = tid >> 6, ln = tid & 63;
        int row = (blk - 1) * 4 + grp;             // b*48+i, < 192
        int b = row / NN, i = row % NN;
        float* sin1 = smem + grp * 64;
        float* sh1  = smem + 256 + grp * 64;
        int c = ln & 15, q = ln >> 4;
        float ex = 0.f, fa = 1.f;
        const float* xb = x2 + (size_t)row * NN * 16 + c;
        for (int jj = q * 12; jj < q * 12 + 12; ++jj) {
            float v = xb[jj * 16];
            bool ok = (jj != i);
            ex = fmaxf(ex, ok ? v : 0.f); fa = fminf(fa, ok ? v : 1.f);
        }
        ex = fmaxf(ex, __shfl_xor(ex, 16)); fa = fminf(fa, __shfl_xor(fa, 16));
        ex = fmaxf(ex, __shfl_xor(ex, 32)); fa = fminf(fa, __shfl_xor(fa, 32));
        if (q == 0) { sin1[32 + 2 * c] = ex; sin1[33 + 2 * c] = fa; }
        if (ln < 16) sin1[ln] = x0[b * 16 + ln];
        else if (ln < 32) sin1[ln] = x1[row * 16 + (ln - 16)];
        __syncthreads();
        float h = b1_1[ln];
        #pragma unroll
        for (int c4 = 0; c4 < 64; c4 += 4) {
            float4 iv = *(const float4*)&sin1[c4];
            h += iv.x * W1_1[(c4 + 0) * 64 + ln] + iv.y * W1_1[(c4 + 1) * 64 + ln]
               + iv.z * W1_1[(c4 + 2) * 64 + ln] + iv.w * W1_1[(c4 + 3) * 64 + ln];
        }
        sh1[ln] = fmaxf(h, 0.f);
        __syncthreads();
        if (ln < 16) {
            float acc = b2_1[ln];
            #pragma unroll
            for (int tt = 0; tt < 64; ++tt) acc += sh1[tt] * W2_1[tt * 16 + ln];
            out[64 + row * 16 + ln] = sigmoidf_(acc);
        }
    } else {
        float* sW1  = smem;            // 8192
        float* sin_ = smem + 8192;     // [4][128]
        float* sh   = smem + 8704;     // [4][64]
        int wv = tid >> 6, ln = tid & 63;
        for (int p = tid; p < 8192; p += 256) sW1[p] = W1_2[p];
        float bias = b1_2[ln];
        __syncthreads();
        for (int rr = 0; rr < 4; ++rr) {
            int row = (blk - 49) * 16 + rr * 4 + wv;   // (b*48+i)*48+j
            int j = row % NN;
            int bi = row / NN;
            int i = bi % NN;
            int b = bi / NN;
            for (int cc = ln; cc < 128; cc += 64) {
                int half = cc >> 6, w = cc & 63;
                int a1 = half ? j : i;
                int a2 = half ? i : j;
                float v;
                if (w < 16)      v = x1[(b * NN + a1) * 16 + w];
                else if (w < 32) v = x2[((b * NN + a1) * NN + a2) * 16 + (w - 16)];
                else             v = r3[((size_t)(b * NN + a1) * NN + a2) * 32 + (w - 32)];
                sin_[wv * 128 + cc] = v;
            }
            __syncthreads();
            float h = bias;
            #pragma unroll
            for (int c4 = 0; c4 < 128; c4 += 4) {
                float4 iv = *(const float4*)&sin_[wv * 128 + c4];
                h += iv.x * sW1[(c4 + 0) * 64 + ln] + iv.y * sW1[(c4 + 1) * 64 + ln]
                   + iv.z * sW1[(c4 + 2) * 64 + ln] + iv.w * sW1[(c4 + 3) * 64 + ln];
            }
            sh[wv * 64 + ln] = fmaxf(h, 0.f);
            __syncthreads();
            if (ln < 16) {
                float acc = b2_2[ln];
                #pragma unroll
                for (int tt = 0; tt < 64; ++tt) acc += sh[wv * 64 + tt] * W2_2[tt * 16 + ln];
                out[3136 + row * 16 + ln] = sigmoidf_(acc);
            }
            __syncthreads();
        }
    }
}

// ================= kernel C (fast): group 3, mt-per-wave paired MFMA, COALESCED gather ======
// Block = (pair i<=j, batch b), 192 threads = 3 waves, wave = M-tile mt. All fragments are
// kk-innermost (stride 16 elem) via the 3 x3 layouts {x3bf, Z, Y} + x2t. Offsets relative
// to the single bf16 ws base (x2bf): x2t +147456, x3 +294912, Z +7372800, Y +14450688.
__global__ __launch_bounds__(192) void k_g3d(const unsigned short* __restrict__ wsb,
        const unsigned short* __restrict__ wf,
        const float* __restrict__ b1, const float* __restrict__ b2,
        float* __restrict__ out3) {
    __shared__ __align__(16) unsigned short sH[2][6 * 64 * 8];   // 12 KB

    int tid = threadIdx.x, mt = tid >> 6, l = tid & 63;   // wave = M-tile 0..2
    int pp = blockIdx.x, i = 0;
    while (pp >= NN - i) { pp -= NN - i; ++i; }
    int j = i + pp;                               // i <= j
    int b = blockIdx.y;

    bf16x8 w1f[4][6];
    #pragma unroll
    for (int nt = 0; nt < 4; ++nt)
        #pragma unroll
        for (int ks = 0; ks < 6; ++ks)
            w1f[nt][ks] = *(const bf16x8*)(wf + (((nt * 6 + ks) << 6) + l) * 8);
    bf16x8 w2f[2];
    #pragma unroll
    for (int ks = 0; ks < 2; ++ks)
        w2f[ks] = *(const bf16x8*)(wf + 12288 + ((ks << 6) + l) * 8);

    const int b2b = b * 36864;                    // batch offset within x2-family
    const int b3b = b * 1769472;                  // batch offset within x3-family
    const int p1[6] = { 2, 4, 0, 5, 1, 3 };

    int l15 = l & 15, g = l >> 4;
    bool isx2 = (g < 2);                          // lanes g=0,1: x2 half; g=2,3: x3 half
    int goff = (g & 1) << 3;
    int ij16 = (i * NN + j) * 16, ji16 = (j * NN + i) * 16;
    int row16 = ((mt << 4) + l15) << 4;           // (mt*16+l15)*16

    int off_[6];
    if (isx2) {
        off_[0] = b2b + ij16 + goff;                       // x2[i][j] broadcast
        off_[1] = b2b + i * 768 + row16 + goff;            // x2[i][kk]
        off_[2] = b2b + ji16 + goff;                       // x2[j][i] broadcast
        off_[3] = 147456 + b2b + i * 768 + row16 + goff;   // x2t[i][kk] = x2[kk][i]
        off_[4] = b2b + j * 768 + row16 + goff;            // x2[j][kk]
        off_[5] = 147456 + b2b + j * 768 + row16 + goff;   // x2t[j][kk] = x2[kk][j]
    } else {
        int ij768 = (i * NN + j) * 768, ji768 = (j * NN + i) * 768;
        off_[0] = 294912   + b3b + ij768 + row16 + goff;   // x3[i][j][kk]
        off_[1] = 7372800  + b3b + ij768 + row16 + goff;   // Z[i][j][kk] = x3[i][kk][j]
        off_[2] = 294912   + b3b + ji768 + row16 + goff;   // x3[j][i][kk]
        off_[3] = 14450688 + b3b + ij768 + row16 + goff;   // Y[i][j][kk] = x3[kk][i][j]
        off_[4] = 7372800  + b3b + ji768 + row16 + goff;   // Z[j][i][kk] = x3[j][kk][i]
        off_[5] = 14450688 + b3b + ji768 + row16 + goff;   // Y[j][i][kk] = x3[kk][j][i]
    }

    f32x4 acc[4][2];
    #pragma unroll
    for (int nt = 0; nt < 4; ++nt) {
        float bv = b1[(nt << 4) + l15];
        f32x4 t = {bv, bv, bv, bv};
        acc[nt][0] = t; acc[nt][1] = t;
    }

    #pragma unroll
    for (int f = 0; f < 6; ++f) {
        bf16x8 a = *(const bf16x8*)(wsb + off_[f]);
        #pragma unroll
        for (int nt = 0; nt < 4; ++nt) {
            acc[nt][0] = __builtin_amdgcn_mfma_f32_16x16x32_bf16(a, w1f[nt][f], acc[nt][0], 0, 0, 0);
            acc[nt][1] = __builtin_amdgcn_mfma_f32_16x16x32_bf16(a, w1f[nt][p1[f]], acc[nt][1], 0, 0, 0);
        }
    }

    // ---- ReLU -> bf16 -> sH (layer-2 A-fragment order), both triples; wave-private ----
    {
        int rbase = (l >> 4) << 2;
        #pragma unroll
        for (int tr = 0; tr < 2; ++tr) {
            #pragma unroll
            for (int nt = 0; nt < 4; ++nt) {
                int within = ((nt & 1) << 4) + l15;   // hc & 31
                int ks2 = nt >> 1;                    // hc >> 5
                int lhi = (within >> 3) << 4;
                int idx = within & 7;
                #pragma unroll
                for (int rg = 0; rg < 4; ++rg) {
                    float h = fmaxf(acc[nt][tr][rg], 0.0f);
                    int lp = rbase + rg + lhi;
                    sH[tr][((((mt << 1) + ks2) << 6) + lp) * 8 + idx] = f2bf(h);
                }
            }
        }
    }
    // no barrier: wave mt writes and reads only segments 2mt, 2mt+1 (lgkmcnt orders it)

    // ---- layer 2: wave mt computes its M-tile, both triples ----
    {
        float bv2 = b2[l15];
        #pragma unroll
        for (int tr = 0; tr < 2; ++tr) {
            if (tr == 0 || i != j) {
                f32x4 acc2 = {bv2, bv2, bv2, bv2};
                #pragma unroll
                for (int ks = 0; ks < 2; ++ks) {
                    bf16x8 a = *(const bf16x8*)&sH[tr][((((mt << 1) + ks) << 6) + l) << 3];
                    acc2 = __builtin_amdgcn_mfma_f32_16x16x32_bf16(a, w2f[ks], acc2, 0, 0, 0);
                }
                int triple = tr ? ((b * NN + j) * NN + i) : ((b * NN + i) * NN + j);
                size_t obase = ((size_t)triple * NN + (mt << 4) + ((l >> 4) << 2)) * 16 + l15;
                #pragma unroll
                for (int rg = 0; rg < 4; ++rg)
                    out3[obase + (size_t)rg * 16] = sigmoidf_(acc2[rg]);
            }
        }
    }
}

// ================= kernel C (fallback): round-4-verified fp32 staged version =================
__global__ __launch_bounds__(256) void k_g3m(const float* __restrict__ x2, const float* __restrict__ x3,
                                             const unsigned short* __restrict__ wf,
                                             const float* __restrict__ b1, const float* __restrict__ b2,
                                             float* __restrict__ out3) {
    __shared__ __align__(16) unsigned short sA[18 * 64 * 8];
    __shared__ __align__(16) unsigned short sH[6 * 64 * 8];

    int tid = threadIdx.x;
    int wv = tid >> 6, l = tid & 63;
    int triple = blockIdx.x;
    int j = triple % NN;
    int bi = triple / NN;
    int i = bi % NN;
    int b = bi / NN;

    bf16x8 w1f[6];
    #pragma unroll
    for (int ks = 0; ks < 6; ++ks)
        w1f[ks] = *(const bf16x8*)(wf + (((wv * 6 + ks) << 6) + l) * 8);
    bf16x8 w2f[2];
    #pragma unroll
    for (int ks = 0; ks < 2; ++ks)
        w2f[ks] = *(const bf16x8*)(wf + 12288 + ((ks << 6) + l) * 8);

    const int x2b = b * NN * NN * 16;
    const int x3b = b * NN * NN * NN * 16;

    #pragma unroll
    for (int it = 0; it < 9; ++it) {
        int t = it * 256 + tid;
        int fs = __builtin_amdgcn_readfirstlane(t >> 7);
        int mt = fs / 6;
        int ks = fs - mt * 6;
        int lp = (t >> 1) & 63;
        int kk = (mt << 4) + (lp & 15);
        int w = ((lp >> 4) << 3) + ((t & 1) << 2);
        int a1, a2, a3;
        switch (ks) {
            case 0:  a1 = i;  a2 = j;  a3 = kk; break;
            case 1:  a1 = i;  a2 = kk; a3 = j;  break;
            case 2:  a1 = j;  a2 = i;  a3 = kk; break;
            case 3:  a1 = kk; a2 = i;  a3 = j;  break;
            case 4:  a1 = j;  a2 = kk; a3 = i;  break;
            default: a1 = kk; a2 = j;  a3 = i;  break;
        }
        const float* p2 = x2 + x2b + (a1 * NN + a2) * 16 + w;
        const float* p3 = x3 + x3b + ((a1 * NN + a2) * NN + a3) * 16 + (w - 16);
        const float* p = (w < 16) ? p2 : p3;
        float4 v = *(const float4*)p;
        uint2 pk;
        pk.x = packbf2(v.x, v.y);
        pk.y = packbf2(v.z, v.w);
        *(uint2*)&sA[t * 4] = pk;
    }
    __syncthreads();

    float bv = b1[(wv << 4) + (l & 15)];
    f32x4 acc0 = {bv, bv, bv, bv};
    f32x4 acc1 = acc0, acc2 = acc0;
    #pragma unroll
    for (int ks = 0; ks < 6; ++ks) {
        bf16x8 a0  = *(const bf16x8*)&sA[(((0 * 6 + ks) << 6) + l) << 3];
        bf16x8 a1_ = *(const bf16x8*)&sA[(((1 * 6 + ks) << 6) + l) << 3];
        bf16x8 a2_ = *(const bf16x8*)&sA[(((2 * 6 + ks) << 6) + l) << 3];
        acc0 = __builtin_amdgcn_mfma_f32_16x16x32_bf16(a0,  w1f[ks], acc0, 0, 0, 0);
        acc1 = __builtin_amdgcn_mfma_f32_16x16x32_bf16(a1_, w1f[ks], acc1, 0, 0, 0);
        acc2 = __builtin_amdgcn_mfma_f32_16x16x32_bf16(a2_, w1f[ks], acc2, 0, 0, 0);
    }

    {
        int within = ((wv & 1) << 4) + (l & 15);
        int ks2 = wv >> 1;
        int lhi = (within >> 3) << 4;
        int idx = within & 7;
        int rbase = (l >> 4) << 2;
        #pragma unroll
        for (int mt = 0; mt < 3; ++mt) {
            f32x4 a = (mt == 0) ? acc0 : (mt == 1) ? acc1 : acc2;
            #pragma unroll
            for (int rg = 0; rg < 4; ++rg) {
                float h = fmaxf(a[rg], 0.0f);
                int lp = rbase + rg + lhi;
                sH[((((mt << 1) + ks2) << 6) + lp) * 8 + idx] = f2bf(h);
            }
        }
    }
    __syncthreads();

    if (wv < 3) {
        int mt = wv;
        float bv2 = b2[l & 15];
        f32x4 acc = {bv2, bv2, bv2, bv2};
        #pragma unroll
        for (int ks = 0; ks < 2; ++ks) {
            bf16x8 a = *(const bf16x8*)&sH[((((mt << 1) + ks) << 6) + l) << 3];
            acc = __builtin_amdgcn_mfma_f32_16x16x32_bf16(a, w2f[ks], acc, 0, 0, 0);
        }
        size_t obase = ((size_t)triple * NN + (mt << 4) + ((l >> 4) << 2)) * 16 + (l & 15);
        #pragma unroll
        for (int rg = 0; rg < 4; ++rg)
            out3[obase + (size_t)rg * 16] = sigmoidf_(acc[rg]);
    }
}

extern "C" void kernel_launch(void* const* d_in, const int* in_sizes, int n_in,
                              void* d_out, int out_size, void* d_ws, size_t ws_size,
                              hipStream_t stream) {
    const float* x0 = (const float*)d_in[0];
    const float* x1 = (const float*)d_in[1];
    const float* x2 = (const float*)d_in[2];
    const float* x3 = (const float*)d_in[3];
    const float* W1_0 = (const float*)d_in[4];
    const float* b1_0 = (const float*)d_in[5];
    const float* W2_0 = (const float*)d_in[6];
    const float* b2_0 = (const float*)d_in[7];
    const float* W1_1 = (const float*)d_in[8];
    const float* b1_1 = (const float*)d_in[9];
    const float* W2_1 = (const float*)d_in[10];
    const float* b2_1 = (const float*)d_in[11];
    const float* W1_2 = (const float*)d_in[12];
    const float* b1_2 = (const float*)d_in[13];
    const float* W2_2 = (const float*)d_in[14];
    const float* b2_2 = (const float*)d_in[15];
    const float* W1_3 = (const float*)d_in[16];
    const float* b1_3 = (const float*)d_in[17];
    const float* W2_3 = (const float*)d_in[18];
    const float* b2_3 = (const float*)d_in[19];

    float* out = (float*)d_out;
    float* r3 = (float*)d_ws;                               // 294912 f32
    unsigned short* wf   = (unsigned short*)(r3 + 294912);  // 13312 bf16
    unsigned short* x2bf = wf + 13312;                      // 147456   (bf16 ws base for k_g3d)
    unsigned short* x2t  = x2bf + 147456;                   // 147456
    unsigned short* x3bf = x2t + 147456;                    // 7077888
    unsigned short* zbf  = x3bf + 7077888;                  // 7077888
    unsigned short* ybf  = zbf + 7077888;                   // 7077888
    size_t need = (size_t)294912 * 4
                + (size_t)(13312 + 2 * 147456 + 3 * 7077888) * 2;   // ~44.3 MB
    int fast = (ws_size >= need) ? 1 : 0;

    hipLaunchKernelGGL(k_pre, dim3(2341), dim3(256), 0, stream,
                       x2, x3, W1_3, W2_3, r3, wf, x2bf, x2t, x3bf, zbf, ybf, fast);
    if (fast)
        hipLaunchKernelGGL(k_g3d, dim3(1176, 4), dim3(192), 0, stream,
                           x2bf, wf, b1_3, b2_3, out + 150592);
    else
        hipLaunchKernelGGL(k_g3m, dim3(9216), dim3(256), 0, stream,
                           x2, x3, wf, b1_3, b2_3, out + 150592);
    hipLaunchKernelGGL(k_small, dim3(625), dim3(256), 0, stream,
                       x0, x1, x2, r3,
                       W1_0, b1_0, W2_0, b2_0,
                       W1_1, b1_1, W2_1, b2_1,
                       W1_2, b1_2, W2_2, b2_2,
                       out);
}